// Round 7
// baseline (211.863 us; speedup 1.0000x reference)
//
#include <hip/hip_runtime.h>

// HMULayer omega: out[b][n] = exp(-(lam_n*||x_b-mu_n||^2 + sum_k om_nk*((x_b-mu_n).v_nk)^2)/D)
// B=1024, N=8192, D=256, K=8. 9 fused bf16 MFMA GEMMs sharing A=x.
// R7: A-tile (64KB, contiguous in swizzled layout) staged to LDS ONCE via glds
//     (1 barrier total); B streamed from global with manual 1-kt-deep register
//     double-buffer (no per-kt barriers -> fine-grained vmcnt pipelining).
//     R6 lesson: af[2][8] preload (64 VGPR live) caused 32MB spill; A now lives
//     in LDS, registers spent on B prefetch instead. Block swizzle: bx>>3 = ng
//     so the 8 b-blocks sharing a pw slice are dispatch-adjacent.

#define B_SZ 1024
#define N_SZ 8192
#define D_SZ 256
#define K_SZ 8

#define BT 128
#define NT 16

typedef __bf16 bf16x8 __attribute__((ext_vector_type(8)));
typedef float f32x4 __attribute__((ext_vector_type(4)));
typedef unsigned short u16x8 __attribute__((ext_vector_type(8)));
typedef unsigned short ushort_t;

// ws byte offsets
#define WS_X2   0u          // f32[1024]
#define WS_MU2  4096u       // f32[8192]
#define WS_MUV  36864u      // f32[65536]
#define WS_PX   299008u     // bf16[1024*256] swizzled (512 KB)
#define WS_PW   823296u     // bf16[8192*9*256] swizzled (36 MB)
#define WS_NEED (823296ull + 37748736ull)

__device__ __forceinline__ float wave_reduce(float s) {
#pragma unroll
  for (int off = 32; off > 0; off >>= 1) s += __shfl_down(s, off);
  return s;
}

__device__ __forceinline__ u16x8 cvt8(const float* sp) {
  u16x8 o;
#pragma unroll
  for (int e = 0; e < 8; ++e)
    o[e] = __builtin_bit_cast(unsigned short, (__bf16)sp[e]);
  return o;
}

__device__ __forceinline__ void glds16(const void* g, const void* l) {
  __builtin_amdgcn_global_load_lds(
      (const __attribute__((address_space(1))) void*)g,
      (__attribute__((address_space(3))) void*)l, 16, 0, 0);
}

// ---- prep_x: x2[b] + swizzled px pack. Block 256 per 16-row group (64 blocks).
// px_p granule: offset16B((g,kt,slot)) = (g*8+kt)*64 + slot, slot = c*16 + r,
// holding x[g*16+r][kt*32 + c*8 .. +8) as 8 bf16.  (validated R5/R6)
__global__ void prep_x(const float* __restrict__ x, float* __restrict__ x2,
                       ushort_t* __restrict__ px_p) {
  __shared__ float xl[16 * 260];
  const int g = blockIdx.x, t = threadIdx.x;
  const int r = t >> 4, c16 = t & 15;
  {
    const float* src = x + ((size_t)(g * 16 + r)) * D_SZ + c16 * 16;
#pragma unroll
    for (int i = 0; i < 4; ++i)
      *(float4*)(xl + r * 260 + c16 * 16 + 4 * i) = *(const float4*)(src + 4 * i);
  }
  __syncthreads();
  const int w = t >> 6, lane = t & 63;
#pragma unroll
  for (int rr = 0; rr < 4; ++rr) {
    int row = w * 4 + rr;
    const float* rp = xl + row * 260 + lane * 4;
    float s = rp[0] * rp[0] + rp[1] * rp[1] + rp[2] * rp[2] + rp[3] * rp[3];
    s = wave_reduce(s);
    if (lane == 0) x2[g * 16 + row] = s;
  }
#pragma unroll
  for (int i = 0; i < 2; ++i) {
    int q = t + 256 * i;
    int kt = q >> 6, slot = q & 63;
    int c = slot >> 4, rw = slot & 15;
    const float* sp = xl + rw * 260 + kt * 32 + c * 8;
    *(u16x8*)(px_p + (((size_t)g * 8 + kt) * 64 + slot) * 8) = cvt8(sp);
  }
}

// ---- prep_w: mu2, muv, swizzled pw pack. Block 256 per 16-n group (512 blocks).
// pw_p granule: offset16B = ((ng*9 + j)*8 + kt)*64 + slot, slot = c*16 + r.
// (validated R5/R6)
__global__ void prep_w(const float* __restrict__ mu, const float* __restrict__ v,
                       float* __restrict__ mu2, float* __restrict__ muv,
                       ushort_t* __restrict__ pw_p) {
  __shared__ float muL[16 * 260];
  __shared__ float vL[16 * 260];
  const int ng = blockIdx.x, t = threadIdx.x;
  const int r = t >> 4, c16 = t & 15;
  const int w = t >> 6, lane = t & 63;
  {
    const float* src = mu + ((size_t)(ng * 16 + r)) * D_SZ + c16 * 16;
#pragma unroll
    for (int i = 0; i < 4; ++i)
      *(float4*)(muL + r * 260 + c16 * 16 + 4 * i) = *(const float4*)(src + 4 * i);
  }
  __syncthreads();
#pragma unroll
  for (int rr = 0; rr < 4; ++rr) {
    int row = w * 4 + rr;
    const float* rp = muL + row * 260 + lane * 4;
    float s = rp[0] * rp[0] + rp[1] * rp[1] + rp[2] * rp[2] + rp[3] * rp[3];
    s = wave_reduce(s);
    if (lane == 0) mu2[ng * 16 + row] = s;
  }
#pragma unroll
  for (int i = 0; i < 2; ++i) {
    int q = t + 256 * i;
    int kt = q >> 6, slot = q & 63;
    int c = slot >> 4, rw = slot & 15;
    const float* sp = muL + rw * 260 + kt * 32 + c * 8;
    *(u16x8*)(pw_p + ((((size_t)ng * 9 + 0) * 8 + kt) * 64 + slot) * 8) = cvt8(sp);
  }
  for (int j = 1; j <= 8; ++j) {
    __syncthreads();
    {
      const float* src = v + (((size_t)(ng * 16 + r)) * K_SZ + (j - 1)) * D_SZ + c16 * 16;
#pragma unroll
      for (int i = 0; i < 4; ++i)
        *(float4*)(vL + r * 260 + c16 * 16 + 4 * i) = *(const float4*)(src + 4 * i);
    }
    __syncthreads();
#pragma unroll
    for (int rr = 0; rr < 4; ++rr) {
      int row = w * 4 + rr;
      const float* ap = muL + row * 260 + lane * 4;
      const float* bp = vL + row * 260 + lane * 4;
      float s = ap[0] * bp[0] + ap[1] * bp[1] + ap[2] * bp[2] + ap[3] * bp[3];
      s = wave_reduce(s);
      if (lane == 0) muv[(ng * 16 + row) * K_SZ + (j - 1)] = s;
    }
#pragma unroll
    for (int i = 0; i < 2; ++i) {
      int q = t + 256 * i;
      int kt = q >> 6, slot = q & 63;
      int c = slot >> 4, rw = slot & 15;
      const float* sp = vL + rw * 260 + kt * 32 + c * 8;
      *(u16x8*)(pw_p + ((((size_t)ng * 9 + j) * 8 + kt) * 64 + slot) * 8) = cvt8(sp);
    }
  }
}

// ---- main: A-tile in LDS (staged once), B double-buffered from global ----
__global__ __launch_bounds__(256, 2)
void hmu_main_p(const ushort_t* __restrict__ px_p,
                const ushort_t* __restrict__ pw_p,
                const float* __restrict__ lam, const float* __restrict__ om,
                const float* __restrict__ wsf, float* __restrict__ out) {
  // Full A tile: 8 row-groups x 8 kt x 1KB granules = 64 KB, linear [g][kt][slot]
  __shared__ __align__(16) ushort_t As[8 * 8 * 512];

  const float* ws_x2 = wsf;
  const float* ws_mu2 = wsf + 1024;
  const float* ws_muv = wsf + 9216;

  const int tid = threadIdx.x;
  const int lane = tid & 63;
  const int w = tid >> 6;
  const int m = lane & 15;
  const int kg = lane >> 4;

  const int bx = blockIdx.x;          // 0..4095, swizzled: 8 b-blocks per ng adjacent
  const int ng = bx >> 3;
  const int by = bx & 7;
  const int n0 = ng * NT;
  const int g0 = by * 8;
  const int b0 = by * BT;

  // --- stage whole A tile once: global granules (g0*8 .. g0*8+63) are contiguous ---
  const ushort_t* pxa = px_p + (size_t)g0 * 8 * 512;   // 64 KB region
#pragma unroll
  for (int t = 0; t < 16; ++t) {
    int gid = w * 16 + t;
    glds16(pxa + (size_t)gid * 512 + lane * 8, As + (size_t)gid * 512);
  }

  f32x4 acc[2][9];
#pragma unroll
  for (int bs = 0; bs < 2; ++bs)
#pragma unroll
    for (int j = 0; j < 9; ++j) acc[bs][j] = (f32x4){0.f, 0.f, 0.f, 0.f};

  // --- B stream base: fragment (j,kt) at pwb + (j*8+kt)*512 shorts ---
  const ushort_t* pwb = pw_p + (size_t)ng * 9 * 4096 + (size_t)lane * 8;

  // prefetch kt=0 while glds completes
  bf16x8 bcur[9], bnxt[9];
#pragma unroll
  for (int j = 0; j < 9; ++j)
    bcur[j] = *(const bf16x8*)(pwb + (size_t)j * 4096);

  __syncthreads();   // single barrier: A tile resident

  const int ga = (2 * w) * 8, gb = (2 * w + 1) * 8;   // granule rows for subtiles
#pragma unroll
  for (int kt = 0; kt < 8; ++kt) {
    if (kt < 7) {
#pragma unroll
      for (int j = 0; j < 9; ++j)
        bnxt[j] = *(const bf16x8*)(pwb + ((size_t)j * 8 + kt + 1) * 512);
    }
    bf16x8 af0 = *(const bf16x8*)&As[(size_t)(ga + kt) * 512 + lane * 8];
    bf16x8 af1 = *(const bf16x8*)&As[(size_t)(gb + kt) * 512 + lane * 8];
#pragma unroll
    for (int j = 0; j < 9; ++j) {
      acc[0][j] = __builtin_amdgcn_mfma_f32_16x16x32_bf16(af0, bcur[j], acc[0][j], 0, 0, 0);
      acc[1][j] = __builtin_amdgcn_mfma_f32_16x16x32_bf16(af1, bcur[j], acc[1][j], 0, 0, 0);
    }
    if (kt < 7) {
#pragma unroll
      for (int j = 0; j < 9; ++j) bcur[j] = bnxt[j];
    }
  }

  // epilogue: C/D layout col(n)=m, row(b within subtile)=kg*4+reg
  const int n = n0 + m;
  const float lam_n = lam[n];
  const float mu2_n = ws_mu2[n];
  float omr[8], muvr[8];
#pragma unroll
  for (int k = 0; k < 8; ++k) {
    omr[k] = om[n * 8 + k];
    muvr[k] = ws_muv[n * 8 + k];
  }
#pragma unroll
  for (int bs = 0; bs < 2; ++bs) {
#pragma unroll
    for (int r = 0; r < 4; ++r) {
      int b = b0 + (2 * w + bs) * 16 + kg * 4 + r;
      float x2b = ws_x2[b];
      float c0 = acc[bs][0][r];
      float q = lam_n * (x2b - 2.f * c0 + mu2_n);
#pragma unroll
      for (int k = 0; k < 8; ++k) {
        float p = acc[bs][k + 1][r] - muvr[k];
        q = fmaf(omr[k] * p, p, q);
      }
      out[(size_t)b * N_SZ + n] = __expf(q * (-1.0f / 256.0f));
    }
  }
}

// ================= fallback path (R2-style, proven) =================
typedef unsigned short u16x4 __attribute__((ext_vector_type(4)));

__device__ __forceinline__ void cvt16_store(const float* __restrict__ src,
                                            unsigned short* dst) {
  const float4* p4 = (const float4*)src;
  float fv[16];
#pragma unroll
  for (int e = 0; e < 4; ++e) {
    float4 t = p4[e];
    fv[4 * e + 0] = t.x; fv[4 * e + 1] = t.y;
    fv[4 * e + 2] = t.z; fv[4 * e + 3] = t.w;
  }
  u16x8 lo, hi;
#pragma unroll
  for (int e = 0; e < 8; ++e) {
    lo[e] = __builtin_bit_cast(unsigned short, (__bf16)fv[e]);
    hi[e] = __builtin_bit_cast(unsigned short, (__bf16)fv[e + 8]);
  }
  *(u16x8*)dst = lo;
  *(u16x8*)(dst + 8) = hi;
}

#define LDS_STRIDE 40
#define FBT 128
__global__ __launch_bounds__(256, 2)
void hmu_main_f(const float* __restrict__ x, const float* __restrict__ mu,
                const float* __restrict__ lam, const float* __restrict__ v,
                const float* __restrict__ om, const float* __restrict__ ws,
                float* __restrict__ out) {
  __shared__ __align__(16) unsigned short As[FBT * LDS_STRIDE];
  __shared__ __align__(16) unsigned short Bs[NT * 9 * LDS_STRIDE];
  const float* ws_x2 = ws;
  const float* ws_mu2 = ws + 1024;
  const float* ws_muv = ws + 9216;
  const int tid = threadIdx.x, lane = tid & 63, w = tid >> 6;
  const int m = lane & 15, kg = lane >> 4;
  const int n0 = blockIdx.x * NT, b0 = blockIdx.y * FBT;
  f32x4 acc[2][9];
#pragma unroll
  for (int bs = 0; bs < 2; ++bs)
#pragma unroll
    for (int j = 0; j < 9; ++j) acc[bs][j] = (f32x4){0.f, 0.f, 0.f, 0.f};
  const int arow = tid >> 1, ahalf = tid & 1;
  for (int kt = 0; kt < 8; ++kt) {
    const int k0 = kt * 32;
    cvt16_store(x + (size_t)(b0 + arow) * D_SZ + k0 + ahalf * 16,
                &As[arow * LDS_STRIDE + ahalf * 16]);
#pragma unroll
    for (int it = 0; it < 2; ++it) {
      int idx = tid + 256 * it;
      if (idx < 288) {
        int row = idx >> 1, half = idx & 1;
        int nl = row / 9, j = row - nl * 9;
        const float* src = (j == 0)
            ? mu + (size_t)(n0 + nl) * D_SZ + k0 + half * 16
            : v + (size_t)((n0 + nl) * K_SZ + (j - 1)) * D_SZ + k0 + half * 16;
        cvt16_store(src, &Bs[row * LDS_STRIDE + half * 16]);
      }
    }
    __syncthreads();
    bf16x8 af[2];
#pragma unroll
    for (int bs = 0; bs < 2; ++bs)
      af[bs] = *(const bf16x8*)&As[((2 * w + bs) * 16 + m) * LDS_STRIDE + kg * 8];
#pragma unroll
    for (int j = 0; j < 9; ++j) {
      bf16x8 bfr = *(const bf16x8*)&Bs[(m * 9 + j) * LDS_STRIDE + kg * 8];
      acc[0][j] = __builtin_amdgcn_mfma_f32_16x16x32_bf16(af[0], bfr, acc[0][j], 0, 0, 0);
      acc[1][j] = __builtin_amdgcn_mfma_f32_16x16x32_bf16(af[1], bfr, acc[1][j], 0, 0, 0);
    }
    __syncthreads();
  }
  const int n = n0 + m;
  const float lam_n = lam[n];
  const float mu2_n = ws_mu2[n];
  float omr[8], muvr[8];
#pragma unroll
  for (int k = 0; k < 8; ++k) {
    omr[k] = om[n * 8 + k];
    muvr[k] = ws_muv[n * 8 + k];
  }
#pragma unroll
  for (int bs = 0; bs < 2; ++bs)
#pragma unroll
    for (int r = 0; r < 4; ++r) {
      int b = b0 + (2 * w + bs) * 16 + kg * 4 + r;
      float c0 = acc[bs][0][r];
      float q = lam_n * (ws_x2[b] - 2.f * c0 + mu2_n);
#pragma unroll
      for (int k = 0; k < 8; ++k) {
        float p = acc[bs][k + 1][r] - muvr[k];
        q = fmaf(omr[k] * p, p, q);
      }
      out[(size_t)b * N_SZ + n] = __expf(q * (-1.0f / 256.0f));
    }
}

__global__ void p2_mu_f(const float* __restrict__ mu, const float* __restrict__ v,
                        float* __restrict__ mu2, float* __restrict__ muv) {
  __shared__ __align__(16) float mulds[D_SZ];
  const int n = blockIdx.x;
  const int w = threadIdx.x >> 6, lane = threadIdx.x & 63;
  if (w == 0) {
    float4 m4 = *(const float4*)(mu + (size_t)n * D_SZ + 4 * lane);
    *(float4*)(mulds + 4 * lane) = m4;
    float s = m4.x * m4.x + m4.y * m4.y + m4.z * m4.z + m4.w * m4.w;
    s = wave_reduce(s);
    if (lane == 0) mu2[n] = s;
  }
  __syncthreads();
  float4 m4 = *(const float4*)(mulds + 4 * lane);
#pragma unroll
  for (int kk = 0; kk < 2; ++kk) {
    const int k = w * 2 + kk;
    float4 v4 = *(const float4*)(v + ((size_t)n * K_SZ + k) * D_SZ + 4 * lane);
    float s = m4.x * v4.x + m4.y * v4.y + m4.z * v4.z + m4.w * v4.w;
    s = wave_reduce(s);
    if (lane == 0) muv[n * K_SZ + k] = s;
  }
}

__global__ void p1_x2_f(const float* __restrict__ x, float* __restrict__ x2) {
  const int w = threadIdx.x >> 6, lane = threadIdx.x & 63;
  const int b = blockIdx.x * 4 + w;
  float4 t = *(const float4*)(x + (size_t)b * D_SZ + 4 * lane);
  float s = t.x * t.x + t.y * t.y + t.z * t.z + t.w * t.w;
  s = wave_reduce(s);
  if (lane == 0) x2[b] = s;
}

extern "C" void kernel_launch(void* const* d_in, const int* in_sizes, int n_in,
                              void* d_out, int out_size, void* d_ws, size_t ws_size,
                              hipStream_t stream) {
  const float* x   = (const float*)d_in[0];
  const float* mu  = (const float*)d_in[1];
  const float* lam = (const float*)d_in[2];
  const float* v   = (const float*)d_in[3];
  const float* om  = (const float*)d_in[4];
  float* out = (float*)d_out;
  char* wsb = (char*)d_ws;
  float* wsf = (float*)d_ws;
  float* x2  = (float*)(wsb + WS_X2);
  float* mu2 = (float*)(wsb + WS_MU2);
  float* muv = (float*)(wsb + WS_MUV);

  if (ws_size >= WS_NEED) {
    ushort_t* px_p = (ushort_t*)(wsb + WS_PX);
    ushort_t* pw_p = (ushort_t*)(wsb + WS_PW);
    prep_x<<<B_SZ / 16, 256, 0, stream>>>(x, x2, px_p);
    prep_w<<<N_SZ / 16, 256, 0, stream>>>(mu, v, mu2, muv, pw_p);
    hmu_main_p<<<(N_SZ / NT) * (B_SZ / BT), 256, 0, stream>>>(px_p, pw_p, lam, om, wsf, out);
  } else {
    p1_x2_f<<<B_SZ / 4, 256, 0, stream>>>(x, x2);
    p2_mu_f<<<N_SZ, 256, 0, stream>>>(mu, v, mu2, muv);
    dim3 grid(N_SZ / NT, B_SZ / FBT);
    hmu_main_f<<<grid, 256, 0, stream>>>(x, mu, lam, v, om, wsf, out);
  }
}

// Round 8
// 180.202 us; speedup vs baseline: 1.1757x; 1.1757x over previous
//
#include <hip/hip_runtime.h>

// HMULayer omega: out[b][n] = exp(-(lam_n*||x_b-mu_n||^2 + sum_k om_nk*((x_b-mu_n).v_nk)^2)/D)
// B=1024, N=8192, D=256, K=8. 9 fused bf16 MFMA GEMMs sharing A=x.
// R8: back to R4's proven per-kt glds structure, upgraded:
//   - S=4 b-subtiles/wave (BT=256): DS-read/wave-kt 11->13KB but waves halve
//     -> DS floor 27 -> 16 us. acc[4][9]=144 AGPR + ~60 VGPR <= 256 @ (256,2).
//   - LDS double-buffer, ONE barrier/kt; stage(kt+1) ages a full compute phase.
//   - swizzled granule layout (R5/R7-validated: 0 bank conflicts, glds-compatible).
//   - XCD-correct dispatch: xcd=bx&7, all 4 b-blocks of an ng on one XCD
//     (R7's bx>>3 put them on 8 different XCDs -> FETCH 151MB).

#define B_SZ 1024
#define N_SZ 8192
#define D_SZ 256
#define K_SZ 8

#define BT 256
#define NT 16

typedef __bf16 bf16x8 __attribute__((ext_vector_type(8)));
typedef float f32x4 __attribute__((ext_vector_type(4)));
typedef unsigned short u16x8 __attribute__((ext_vector_type(8)));
typedef unsigned short ushort_t;

// ws byte offsets
#define WS_X2   0u          // f32[1024]
#define WS_MU2  4096u       // f32[8192]
#define WS_MUV  36864u      // f32[65536]
#define WS_PX   299008u     // bf16[1024*256] swizzled (512 KB)
#define WS_PW   823296u     // bf16[8192*9*256] swizzled (36 MB)
#define WS_NEED (823296ull + 37748736ull)

__device__ __forceinline__ float wave_reduce(float s) {
#pragma unroll
  for (int off = 32; off > 0; off >>= 1) s += __shfl_down(s, off);
  return s;
}

__device__ __forceinline__ u16x8 cvt8(const float* sp) {
  u16x8 o;
#pragma unroll
  for (int e = 0; e < 8; ++e)
    o[e] = __builtin_bit_cast(unsigned short, (__bf16)sp[e]);
  return o;
}

__device__ __forceinline__ void glds16(const void* g, const void* l) {
  __builtin_amdgcn_global_load_lds(
      (const __attribute__((address_space(1))) void*)g,
      (__attribute__((address_space(3))) void*)l, 16, 0, 0);
}

// ---- prep_x: x2[b] + swizzled px pack. (validated R5-R7)
// px_p granule: offset16B((g,kt,slot)) = (g*8+kt)*64 + slot, slot = c*16 + r,
// holding x[g*16+r][kt*32 + c*8 .. +8) as 8 bf16.
__global__ void prep_x(const float* __restrict__ x, float* __restrict__ x2,
                       ushort_t* __restrict__ px_p) {
  __shared__ float xl[16 * 260];
  const int g = blockIdx.x, t = threadIdx.x;
  const int r = t >> 4, c16 = t & 15;
  {
    const float* src = x + ((size_t)(g * 16 + r)) * D_SZ + c16 * 16;
#pragma unroll
    for (int i = 0; i < 4; ++i)
      *(float4*)(xl + r * 260 + c16 * 16 + 4 * i) = *(const float4*)(src + 4 * i);
  }
  __syncthreads();
  const int w = t >> 6, lane = t & 63;
#pragma unroll
  for (int rr = 0; rr < 4; ++rr) {
    int row = w * 4 + rr;
    const float* rp = xl + row * 260 + lane * 4;
    float s = rp[0] * rp[0] + rp[1] * rp[1] + rp[2] * rp[2] + rp[3] * rp[3];
    s = wave_reduce(s);
    if (lane == 0) x2[g * 16 + row] = s;
  }
#pragma unroll
  for (int i = 0; i < 2; ++i) {
    int q = t + 256 * i;
    int kt = q >> 6, slot = q & 63;
    int c = slot >> 4, rw = slot & 15;
    const float* sp = xl + rw * 260 + kt * 32 + c * 8;
    *(u16x8*)(px_p + (((size_t)g * 8 + kt) * 64 + slot) * 8) = cvt8(sp);
  }
}

// ---- prep_w: mu2, muv, swizzled pw pack. (validated R5-R7)
// pw_p granule: offset16B = ((ng*9 + j)*8 + kt)*64 + slot, slot = c*16 + r.
__global__ void prep_w(const float* __restrict__ mu, const float* __restrict__ v,
                       float* __restrict__ mu2, float* __restrict__ muv,
                       ushort_t* __restrict__ pw_p) {
  __shared__ float muL[16 * 260];
  __shared__ float vL[16 * 260];
  const int ng = blockIdx.x, t = threadIdx.x;
  const int r = t >> 4, c16 = t & 15;
  const int w = t >> 6, lane = t & 63;
  {
    const float* src = mu + ((size_t)(ng * 16 + r)) * D_SZ + c16 * 16;
#pragma unroll
    for (int i = 0; i < 4; ++i)
      *(float4*)(muL + r * 260 + c16 * 16 + 4 * i) = *(const float4*)(src + 4 * i);
  }
  __syncthreads();
#pragma unroll
  for (int rr = 0; rr < 4; ++rr) {
    int row = w * 4 + rr;
    const float* rp = muL + row * 260 + lane * 4;
    float s = rp[0] * rp[0] + rp[1] * rp[1] + rp[2] * rp[2] + rp[3] * rp[3];
    s = wave_reduce(s);
    if (lane == 0) mu2[ng * 16 + row] = s;
  }
#pragma unroll
  for (int i = 0; i < 2; ++i) {
    int q = t + 256 * i;
    int kt = q >> 6, slot = q & 63;
    int c = slot >> 4, rw = slot & 15;
    const float* sp = muL + rw * 260 + kt * 32 + c * 8;
    *(u16x8*)(pw_p + ((((size_t)ng * 9 + 0) * 8 + kt) * 64 + slot) * 8) = cvt8(sp);
  }
  for (int j = 1; j <= 8; ++j) {
    __syncthreads();
    {
      const float* src = v + (((size_t)(ng * 16 + r)) * K_SZ + (j - 1)) * D_SZ + c16 * 16;
#pragma unroll
      for (int i = 0; i < 4; ++i)
        *(float4*)(vL + r * 260 + c16 * 16 + 4 * i) = *(const float4*)(src + 4 * i);
    }
    __syncthreads();
#pragma unroll
    for (int rr = 0; rr < 4; ++rr) {
      int row = w * 4 + rr;
      const float* ap = muL + row * 260 + lane * 4;
      const float* bp = vL + row * 260 + lane * 4;
      float s = ap[0] * bp[0] + ap[1] * bp[1] + ap[2] * bp[2] + ap[3] * bp[3];
      s = wave_reduce(s);
      if (lane == 0) muv[(ng * 16 + row) * K_SZ + (j - 1)] = s;
    }
#pragma unroll
    for (int i = 0; i < 2; ++i) {
      int q = t + 256 * i;
      int kt = q >> 6, slot = q & 63;
      int c = slot >> 4, rw = slot & 15;
      const float* sp = vL + rw * 260 + kt * 32 + c * 8;
      *(u16x8*)(pw_p + ((((size_t)ng * 9 + j) * 8 + kt) * 64 + slot) * 8) = cvt8(sp);
    }
  }
}

// ---- main: S=4, per-kt glds into double-buffered LDS, one barrier per kt ----
__global__ __launch_bounds__(256, 2)
void hmu_main_p(const ushort_t* __restrict__ px_p,
                const ushort_t* __restrict__ pw_p,
                const float* __restrict__ lam, const float* __restrict__ om,
                const float* __restrict__ wsf, float* __restrict__ out) {
  __shared__ __align__(16) ushort_t As[2][16 * 512];   // 16 KB per buf
  __shared__ __align__(16) ushort_t Bs[2][9 * 512];    // 9 KB per buf

  const float* ws_x2 = wsf;
  const float* ws_mu2 = wsf + 1024;
  const float* ws_muv = wsf + 9216;

  const int tid = threadIdx.x;
  const int lane = tid & 63;
  const int w = tid >> 6;
  const int m = lane & 15;
  const int kg = lane >> 4;

  // XCD-correct dispatch: blocks round-robin XCDs by bx&7. All 4 b-blocks of
  // one ng share xcd and are <=32 dispatch slots apart -> pw slice L2-resident.
  const int bx = blockIdx.x;              // 0..2047
  const int xcd = bx & 7;
  const int t8 = bx >> 3;                 // 0..255
  const int ng = xcd * 64 + (t8 >> 2);    // 0..511
  const int by = t8 & 3;                  // 0..3
  const int n0 = ng * NT;
  const int g0 = by * 16;                 // 16 b-row-groups per block
  const int b0 = by * BT;

  const ushort_t* pwb = pw_p + (size_t)ng * 9 * 4096;  // shorts

  // stage(kt, buf): A granules (g0+gl, kt) gl=0..15; B granules (j, kt) j=0..8
#define STAGE(KT, BUF)                                                        \
  do {                                                                        \
    _Pragma("unroll")                                                         \
    for (int tt = 0; tt < 4; ++tt) {                                          \
      int gl = 4 * w + tt;                                                    \
      glds16(px_p + (((size_t)(g0 + gl) * 8 + (KT)) * 64 + lane) * 8,         \
             &As[BUF][gl * 512]);                                             \
    }                                                                         \
    _Pragma("unroll")                                                         \
    for (int tt = 0; tt < 2; ++tt) {                                          \
      int j = 2 * w + tt;                                                     \
      glds16(pwb + ((size_t)j * 8 + (KT)) * 512 + lane * 8, &Bs[BUF][j * 512]);\
    }                                                                         \
    if (w == 0)                                                               \
      glds16(pwb + ((size_t)8 * 8 + (KT)) * 512 + lane * 8, &Bs[BUF][8 * 512]);\
  } while (0)

  f32x4 acc[4][9];
#pragma unroll
  for (int bs = 0; bs < 4; ++bs)
#pragma unroll
    for (int j = 0; j < 9; ++j) acc[bs][j] = (f32x4){0.f, 0.f, 0.f, 0.f};

  STAGE(0, 0);

#pragma unroll
  for (int kt = 0; kt < 8; ++kt) {
    const int cb = kt & 1;
    __syncthreads();                 // drains prior stage (aged 1 compute phase)
    if (kt < 7) STAGE(kt + 1, cb ^ 1);

    bf16x8 af[4];
#pragma unroll
    for (int bs = 0; bs < 4; ++bs)
      af[bs] = *(const bf16x8*)&As[cb][(4 * w + bs) * 512 + lane * 8];
#pragma unroll
    for (int j = 0; j < 9; ++j) {
      bf16x8 bfr = *(const bf16x8*)&Bs[cb][j * 512 + lane * 8];
#pragma unroll
      for (int bs = 0; bs < 4; ++bs)
        acc[bs][j] = __builtin_amdgcn_mfma_f32_16x16x32_bf16(af[bs], bfr, acc[bs][j], 0, 0, 0);
    }
  }
#undef STAGE

  // epilogue: C/D layout col(n)=m, row(b within subtile)=kg*4+reg (R5-validated S=4)
  const int n = n0 + m;
  const float lam_n = lam[n];
  const float mu2_n = ws_mu2[n];
  float omr[8], muvr[8];
#pragma unroll
  for (int k = 0; k < 8; ++k) {
    omr[k] = om[n * 8 + k];
    muvr[k] = ws_muv[n * 8 + k];
  }
#pragma unroll
  for (int bs = 0; bs < 4; ++bs) {
#pragma unroll
    for (int r = 0; r < 4; ++r) {
      int b = b0 + (4 * w + bs) * 16 + kg * 4 + r;
      float x2b = ws_x2[b];
      float c0 = acc[bs][0][r];
      float q = lam_n * (x2b - 2.f * c0 + mu2_n);
#pragma unroll
      for (int k = 0; k < 8; ++k) {
        float p = acc[bs][k + 1][r] - muvr[k];
        q = fmaf(omr[k] * p, p, q);
      }
      out[(size_t)b * N_SZ + n] = __expf(q * (-1.0f / 256.0f));
    }
  }
}

// ================= fallback path (R2-style, proven) =================
typedef unsigned short u16x4 __attribute__((ext_vector_type(4)));

__device__ __forceinline__ void cvt16_store(const float* __restrict__ src,
                                            unsigned short* dst) {
  const float4* p4 = (const float4*)src;
  float fv[16];
#pragma unroll
  for (int e = 0; e < 4; ++e) {
    float4 t = p4[e];
    fv[4 * e + 0] = t.x; fv[4 * e + 1] = t.y;
    fv[4 * e + 2] = t.z; fv[4 * e + 3] = t.w;
  }
  u16x8 lo, hi;
#pragma unroll
  for (int e = 0; e < 8; ++e) {
    lo[e] = __builtin_bit_cast(unsigned short, (__bf16)fv[e]);
    hi[e] = __builtin_bit_cast(unsigned short, (__bf16)fv[e + 8]);
  }
  *(u16x8*)dst = lo;
  *(u16x8*)(dst + 8) = hi;
}

#define LDS_STRIDE 40
#define FBT 128
__global__ __launch_bounds__(256, 2)
void hmu_main_f(const float* __restrict__ x, const float* __restrict__ mu,
                const float* __restrict__ lam, const float* __restrict__ v,
                const float* __restrict__ om, const float* __restrict__ ws,
                float* __restrict__ out) {
  __shared__ __align__(16) unsigned short As[FBT * LDS_STRIDE];
  __shared__ __align__(16) unsigned short Bs[NT * 9 * LDS_STRIDE];
  const float* ws_x2 = ws;
  const float* ws_mu2 = ws + 1024;
  const float* ws_muv = ws + 9216;
  const int tid = threadIdx.x, lane = tid & 63, w = tid >> 6;
  const int m = lane & 15, kg = lane >> 4;
  const int n0 = blockIdx.x * NT, b0 = blockIdx.y * FBT;
  f32x4 acc[2][9];
#pragma unroll
  for (int bs = 0; bs < 2; ++bs)
#pragma unroll
    for (int j = 0; j < 9; ++j) acc[bs][j] = (f32x4){0.f, 0.f, 0.f, 0.f};
  const int arow = tid >> 1, ahalf = tid & 1;
  for (int kt = 0; kt < 8; ++kt) {
    const int k0 = kt * 32;
    cvt16_store(x + (size_t)(b0 + arow) * D_SZ + k0 + ahalf * 16,
                &As[arow * LDS_STRIDE + ahalf * 16]);
#pragma unroll
    for (int it = 0; it < 2; ++it) {
      int idx = tid + 256 * it;
      if (idx < 288) {
        int row = idx >> 1, half = idx & 1;
        int nl = row / 9, j = row - nl * 9;
        const float* src = (j == 0)
            ? mu + (size_t)(n0 + nl) * D_SZ + k0 + half * 16
            : v + (size_t)((n0 + nl) * K_SZ + (j - 1)) * D_SZ + k0 + half * 16;
        cvt16_store(src, &Bs[row * LDS_STRIDE + half * 16]);
      }
    }
    __syncthreads();
    bf16x8 af[2];
#pragma unroll
    for (int bs = 0; bs < 2; ++bs)
      af[bs] = *(const bf16x8*)&As[((2 * w + bs) * 16 + m) * LDS_STRIDE + kg * 8];
#pragma unroll
    for (int j = 0; j < 9; ++j) {
      bf16x8 bfr = *(const bf16x8*)&Bs[(m * 9 + j) * LDS_STRIDE + kg * 8];
      acc[0][j] = __builtin_amdgcn_mfma_f32_16x16x32_bf16(af[0], bfr, acc[0][j], 0, 0, 0);
      acc[1][j] = __builtin_amdgcn_mfma_f32_16x16x32_bf16(af[1], bfr, acc[1][j], 0, 0, 0);
    }
    __syncthreads();
  }
  const int n = n0 + m;
  const float lam_n = lam[n];
  const float mu2_n = ws_mu2[n];
  float omr[8], muvr[8];
#pragma unroll
  for (int k = 0; k < 8; ++k) {
    omr[k] = om[n * 8 + k];
    muvr[k] = ws_muv[n * 8 + k];
  }
#pragma unroll
  for (int bs = 0; bs < 2; ++bs)
#pragma unroll
    for (int r = 0; r < 4; ++r) {
      int b = b0 + (2 * w + bs) * 16 + kg * 4 + r;
      float c0 = acc[bs][0][r];
      float q = lam_n * (ws_x2[b] - 2.f * c0 + mu2_n);
#pragma unroll
      for (int k = 0; k < 8; ++k) {
        float p = acc[bs][k + 1][r] - muvr[k];
        q = fmaf(omr[k] * p, p, q);
      }
      out[(size_t)b * N_SZ + n] = __expf(q * (-1.0f / 256.0f));
    }
}

__global__ void p2_mu_f(const float* __restrict__ mu, const float* __restrict__ v,
                        float* __restrict__ mu2, float* __restrict__ muv) {
  __shared__ __align__(16) float mulds[D_SZ];
  const int n = blockIdx.x;
  const int w = threadIdx.x >> 6, lane = threadIdx.x & 63;
  if (w == 0) {
    float4 m4 = *(const float4*)(mu + (size_t)n * D_SZ + 4 * lane);
    *(float4*)(mulds + 4 * lane) = m4;
    float s = m4.x * m4.x + m4.y * m4.y + m4.z * m4.z + m4.w * m4.w;
    s = wave_reduce(s);
    if (lane == 0) mu2[n] = s;
  }
  __syncthreads();
  float4 m4 = *(const float4*)(mulds + 4 * lane);
#pragma unroll
  for (int kk = 0; kk < 2; ++kk) {
    const int k = w * 2 + kk;
    float4 v4 = *(const float4*)(v + ((size_t)n * K_SZ + k) * D_SZ + 4 * lane);
    float s = m4.x * v4.x + m4.y * v4.y + m4.z * v4.z + m4.w * v4.w;
    s = wave_reduce(s);
    if (lane == 0) muv[n * K_SZ + k] = s;
  }
}

__global__ void p1_x2_f(const float* __restrict__ x, float* __restrict__ x2) {
  const int w = threadIdx.x >> 6, lane = threadIdx.x & 63;
  const int b = blockIdx.x * 4 + w;
  float4 t = *(const float4*)(x + (size_t)b * D_SZ + 4 * lane);
  float s = t.x * t.x + t.y * t.y + t.z * t.z + t.w * t.w;
  s = wave_reduce(s);
  if (lane == 0) x2[b] = s;
}

extern "C" void kernel_launch(void* const* d_in, const int* in_sizes, int n_in,
                              void* d_out, int out_size, void* d_ws, size_t ws_size,
                              hipStream_t stream) {
  const float* x   = (const float*)d_in[0];
  const float* mu  = (const float*)d_in[1];
  const float* lam = (const float*)d_in[2];
  const float* v   = (const float*)d_in[3];
  const float* om  = (const float*)d_in[4];
  float* out = (float*)d_out;
  char* wsb = (char*)d_ws;
  float* wsf = (float*)d_ws;
  float* x2  = (float*)(wsb + WS_X2);
  float* mu2 = (float*)(wsb + WS_MU2);
  float* muv = (float*)(wsb + WS_MUV);

  if (ws_size >= WS_NEED) {
    ushort_t* px_p = (ushort_t*)(wsb + WS_PX);
    ushort_t* pw_p = (ushort_t*)(wsb + WS_PW);
    prep_x<<<B_SZ / 16, 256, 0, stream>>>(x, x2, px_p);
    prep_w<<<N_SZ / 16, 256, 0, stream>>>(mu, v, mu2, muv, pw_p);
    hmu_main_p<<<(N_SZ / NT) * (B_SZ / BT), 256, 0, stream>>>(px_p, pw_p, lam, om, wsf, out);
  } else {
    p1_x2_f<<<B_SZ / 4, 256, 0, stream>>>(x, x2);
    p2_mu_f<<<N_SZ, 256, 0, stream>>>(mu, v, mu2, muv);
    dim3 grid(N_SZ / NT, B_SZ / FBT);
    hmu_main_f<<<grid, 256, 0, stream>>>(x, mu, lam, v, om, wsf, out);
  }
}